// Round 3
// baseline (227.354 us; speedup 1.0000x reference)
//
#include <hip/hip_runtime.h>
#include <hip/hip_bf16.h>

// HelicalAttention on MI355X (gfx950).
// B=2,S=2048,E=1024,H=16,HD=64,HX=64,P=32. All heavy math in bf16 MFMA,
// fp32 accumulate. Score = (q/16)·k + (qs/8)·(ks/8) folded into one K=128
// contraction; log2(e) folded into Q so softmax uses raw exp2. Flash-style,
// no max subtraction (scores bounded).
// R11: attn = R9 fat-wave datapath (256-q tile, 2 q-sets/wave -> every K/V
// ds_read feeds 2 MFMAs, halving the binding LDS-read traffic) + R10
// counted-vmcnt triple-buffer pipeline (no vmcnt(0) drain in main loop --
// the drain is what killed R9 at 1 block/CU) + T5 setprio around MFMA
// clusters. out_gemm keeps R10 pipeline (it banked ~6 us).

typedef unsigned short u16;
typedef unsigned int u32;
typedef __attribute__((ext_vector_type(8))) __bf16 bf16x8;
typedef __attribute__((ext_vector_type(4))) float f32x4;
typedef __attribute__((ext_vector_type(16))) float f32x16;

union BFrag { u32 u[4]; bf16x8 b; };

__device__ __forceinline__ u16 f2b(float f) {
  u32 u = __float_as_uint(f);
  u32 r = (u + 0x7fffu + ((u >> 16) & 1u)) >> 16;
  return (u16)r;
}
__device__ __forceinline__ float b2f(u16 h) {
  return __uint_as_float(((u32)h) << 16);
}

__device__ __forceinline__ f32x4 mfma16(bf16x8 a, bf16x8 b, f32x4 c) {
  return __builtin_amdgcn_mfma_f32_16x16x32_bf16(a, b, c, 0, 0, 0);
}
__device__ __forceinline__ f32x16 mfma32(bf16x8 a, bf16x8 b, f32x16 c) {
  return __builtin_amdgcn_mfma_f32_32x32x16_bf16(a, b, c, 0, 0, 0);
}

// async global->LDS, 16B per lane. LDS dest = wave-uniform base + lane*16.
__device__ __forceinline__ void gld16(void* lds, const void* g) {
  __builtin_amdgcn_global_load_lds(
      (const __attribute__((address_space(1))) unsigned int*)g,
      (__attribute__((address_space(3))) unsigned int*)lds, 16, 0, 0);
}

// a' = [a.low32, b.low32], b' = [a.high32, b.high32]  (cross-half exchange)
__device__ __forceinline__ void pl32swap(u32& a, u32& b, int l5) {
#if __has_builtin(__builtin_amdgcn_permlane32_swap)
  typedef unsigned int u32x2v __attribute__((ext_vector_type(2)));
  u32x2v r = __builtin_amdgcn_permlane32_swap(a, b, false, false);
  a = r[0];
  b = r[1];
#else
  u32 ea = __shfl_xor((int)a, 32);
  u32 eb = __shfl_xor((int)b, 32);
  u32 na = l5 ? eb : a;
  u32 nb = l5 ? b : ea;
  a = na;
  b = nb;
#endif
}

#define LOG2E 1.4426950408889634f

// counted-vmcnt barrier: each wave confirms its own oldest DMAs done, then
// raw barrier (no compiler drain). sched_barrier fences pin motion.
#define PIPE_BARRIER(N)                                         \
  do {                                                          \
    __builtin_amdgcn_sched_barrier(0);                          \
    asm volatile("s_waitcnt vmcnt(" #N ")" ::: "memory");       \
    __builtin_amdgcn_s_barrier();                               \
    __builtin_amdgcn_sched_barrier(0);                          \
  } while (0)

// ---------------------------------------------------------------- cast -----
__global__ __launch_bounds__(256) void cast_kernel(
    const float* __restrict__ x,  const float* __restrict__ wq,
    const float* __restrict__ wk, const float* __restrict__ wv,
    const float* __restrict__ wo, const float* __restrict__ whel,
    u16* __restrict__ xb, u16* __restrict__ wb, u16* __restrict__ wob,
    u16* __restrict__ whb) {
  long long q = (long long)blockIdx.x * 256 + threadIdx.x;
  const float* s; u16* d; long long base;
  if (q < 1048576)      { s = x;    d = xb;            base = 0; }
  else if (q < 1310720) { s = wq;   d = wb;            base = 1048576; }
  else if (q < 1572864) { s = wk;   d = wb + 1048576;  base = 1310720; }
  else if (q < 1835008) { s = wv;   d = wb + 2097152;  base = 1572864; }
  else if (q < 2097152) { s = wo;   d = wob;           base = 1835008; }
  else                  { s = whel; d = whb;           base = 2097152; }
  long long e = (q - base) * 4;
  float4 v = *(const float4*)(s + e);
  ushort4 o;
  o.x = f2b(v.x); o.y = f2b(v.y); o.z = f2b(v.z); o.w = f2b(v.w);
  *(ushort4*)(d + e) = o;
}

// ------------------------------------------------------- QKV GEMM + hel ----
// which=0 -> Qcat[bh][s][0:64] = q*(log2e/16); which=1 -> Kcat = k;
// which=2 -> vT[bh][d][t] = v via LDS transpose (coalesced stores).
// Fused helical epilogue (which 0/1): wave's 64x64 acc quadrant = one head x
// 64 tokens; hel = acc·Whel[h]^T + bhel -> pair-normalize -> scramble staged
// in LDS (Hs) -> coalesced uint4 stores of cols [64:128).
__global__ __launch_bounds__(256, 3) void qkv_gemm(
    const u16* __restrict__ xb, const u16* __restrict__ wb,
    const float* __restrict__ bq, const float* __restrict__ bk,
    const float* __restrict__ bv, const u16* __restrict__ whb,
    const float* __restrict__ bhel,
    u16* __restrict__ Qcat, u16* __restrict__ Kcat, u16* __restrict__ vt) {
  union SM {
    struct { u16 Al[2][128][32]; u16 Bl[2][128][32]; u16 T[64][136]; } m;
    struct { u16 Th[4][32][72]; u16 Hs[2][128][64]; } e;  // 51200 B
  };
  __shared__ SM sm;
  const int nt = blockIdx.x, mt = blockIdx.y;
  const int which = nt >> 3;
  const int n0 = (nt & 7) << 7;
  const int m0 = mt << 7;
  const int tid = threadIdx.x;
  const int wave = tid >> 6, lane = tid & 63;
  const int g = lane >> 4, c15 = lane & 15;
  const int wm = wave & 1, wn = wave >> 1;
  const u16* Wp = wb + (long long)which * (1024 * 1024) + n0 * 1024;
  const u16* Ap = xb + m0 * 1024;
  const int srow = (wave * 64 + lane) >> 2;  // 0..63
  const int scol = (lane & 3) << 3;          // 0,8,16,24

  f32x4 acc[4][4];
#pragma unroll
  for (int i = 0; i < 4; i++)
#pragma unroll
    for (int j = 0; j < 4; j++) acc[i][j] = f32x4{0.f, 0.f, 0.f, 0.f};

  // prologue: stage k0=0 into buf 0
  gld16(&sm.m.Al[0][srow][scol],      Ap + srow * 1024 + scol);
  gld16(&sm.m.Al[0][64 + srow][scol], Ap + (64 + srow) * 1024 + scol);
  gld16(&sm.m.Bl[0][srow][scol],      Wp + srow * 1024 + scol);
  gld16(&sm.m.Bl[0][64 + srow][scol], Wp + (64 + srow) * 1024 + scol);

  for (int k0 = 0; k0 < 1024; k0 += 32) {
    const int c = (k0 >> 5) & 1;
    __syncthreads();  // waits DMA(k0); prefetch below had full compute to land
    if (k0 + 32 < 1024) {
      const int kn = k0 + 32;
      gld16(&sm.m.Al[c ^ 1][srow][scol],      Ap + srow * 1024 + kn + scol);
      gld16(&sm.m.Al[c ^ 1][64 + srow][scol],
            Ap + (64 + srow) * 1024 + kn + scol);
      gld16(&sm.m.Bl[c ^ 1][srow][scol],      Wp + srow * 1024 + kn + scol);
      gld16(&sm.m.Bl[c ^ 1][64 + srow][scol],
            Wp + (64 + srow) * 1024 + kn + scol);
    }
    bf16x8 a[4], b[4];
#pragma unroll
    for (int i = 0; i < 4; i++)
      a[i] = *(const bf16x8*)&sm.m.Al[c][wm * 64 + i * 16 + c15][g * 8];
#pragma unroll
    for (int j = 0; j < 4; j++)
      b[j] = *(const bf16x8*)&sm.m.Bl[c][wn * 64 + j * 16 + c15][g * 8];
#pragma unroll
    for (int i = 0; i < 4; i++)
#pragma unroll
      for (int j = 0; j < 4; j++) acc[i][j] = mfma16(a[i], b[j], acc[i][j]);
  }

  if (which == 2) {
#pragma unroll
    for (int half = 0; half < 2; ++half) {
      __syncthreads();
      if (wn == half) {
#pragma unroll
        for (int i = 0; i < 4; i++)
#pragma unroll
          for (int j = 0; j < 4; j++)
#pragma unroll
            for (int r = 0; r < 4; r++) {
              int nloc = j * 16 + c15;                  // 0..63
              int mloc = wm * 64 + i * 16 + g * 4 + r;  // 0..127
              float v = acc[i][j][r] + bv[n0 + half * 64 + nloc];
              sm.m.T[nloc][mloc] = f2b(v);
            }
      }
      __syncthreads();
#pragma unroll
      for (int it = 0; it < 4; ++it) {
        int idx = it * 256 + tid;
        int row = idx >> 4;         // 0..63
        int cm = (idx & 15) * 8;    // 0..120
        int col = n0 + half * 64 + row;
        int hh = col >> 6, dd = col & 63;
        int m = m0 + cm;
        int bb2 = m >> 11, s = m & 2047;
        *(uint4*)&vt[(((bb2 * 16 + hh) * 64) + dd) * 2048 + s] =
            *(const uint4*)&sm.m.T[row][cm];
      }
    }
    return;
  }

  // ---------------- fused helical epilogue (which 0 or 1) ----------------
  const float* bias = (which == 0) ? bq : bk;
  const float fold = (which == 0) ? (0.0625f * LOG2E) : 1.0f;
  const float osc  = (which == 0) ? (0.125f * LOG2E) : 0.125f;
  const int h0 = n0 >> 6;
  const int hsel = h0 + wn;  // wave's head (block spans 2 heads)
  u16* Dst = ((which == 0) ? Qcat : Kcat);

  // Whel B-frags direct from global (once per block)
  bf16x8 wf[2][4];  // [kh][nf]
#pragma unroll
  for (int kh = 0; kh < 2; ++kh)
#pragma unroll
    for (int nf = 0; nf < 4; ++nf)
      wf[kh][nf] = *(const bf16x8*)(whb + hsel * 4096 + (nf * 16 + c15) * 64 +
                                    kh * 32 + g * 8);

  __syncthreads();  // all main-loop LDS reads done; safe to repurpose
  const int bb2 = m0 >> 11;
  const int ubase = (m0 & 2047) >> 1;

#pragma unroll
  for (int half = 0; half < 2; ++half) {
    // main output write (cols [0:64)) + per-wave Th tile (raw bf16, no fold)
#pragma unroll
    for (int i2 = 0; i2 < 2; ++i2) {
      int i = half * 2 + i2;
#pragma unroll
      for (int j = 0; j < 4; ++j)
#pragma unroll
        for (int r = 0; r < 4; ++r) {
          int row = m0 + wm * 64 + i * 16 + g * 4 + r;  // token 0..4095
          int col = n0 + wn * 64 + j * 16 + c15;
          float vraw = acc[i][j][r] + bias[col];
          int bb = row >> 11, s = row & 2047;
          int d = col & 63;
          Dst[(((long long)(bb * 16 + hsel) * 2048) + s) * 128 + d] =
              f2b(vraw * fold);
          sm.e.Th[wave][i2 * 16 + g * 4 + r][j * 16 + c15] = f2b(vraw);
        }
    }
    // hel = Th(32 tok x 64 d) · Whel[h]^T   [Th wave-private, in-order LDS]
    f32x4 hacc[2][4];
#pragma unroll
    for (int mf = 0; mf < 2; ++mf)
#pragma unroll
      for (int nf = 0; nf < 4; ++nf) hacc[mf][nf] = f32x4{0.f, 0.f, 0.f, 0.f};
#pragma unroll
    for (int kh = 0; kh < 2; ++kh) {
      bf16x8 a0 = *(const bf16x8*)&sm.e.Th[wave][c15][kh * 32 + g * 8];
      bf16x8 a1 = *(const bf16x8*)&sm.e.Th[wave][16 + c15][kh * 32 + g * 8];
#pragma unroll
      for (int nf = 0; nf < 4; ++nf) {
        hacc[0][nf] = mfma16(a0, wf[kh][nf], hacc[0][nf]);
        hacc[1][nf] = mfma16(a1, wf[kh][nf], hacc[1][nf]);
      }
    }
    // + bhel, pair-normalize (partner e^1 = lane^1), scramble-stage into Hs
#pragma unroll
    for (int mf = 0; mf < 2; ++mf)
#pragma unroll
      for (int nf = 0; nf < 4; ++nf)
#pragma unroll
        for (int r = 0; r < 4; ++r) {
          int e = nf * 16 + c15;
          float v = hacc[mf][nf][r] + bhel[hsel * 64 + e];
          float pp = __shfl_xor(v, 1);
          float nn = sqrtf(v * v + pp * pp);
          float o = v / fmaxf(nn, 1e-12f) * osc;
          int tl = wm * 64 + half * 32 + mf * 16 + g * 4 + r;  // token-local
          sm.e.Hs[wn][(e & 1) * 64 + (tl >> 1)][(e & ~1) | (tl & 1)] = f2b(o);
        }
  }
  __syncthreads();
  // coalesced stores of hel region: 2 heads x 128 Hs-rows x 8 uint4 chunks
#pragma unroll
  for (int it = 0; it < 8; ++it) {
    int idx = it * 256 + tid;  // 0..2047
    int hh = idx >> 10;
    int hr = (idx >> 3) & 127;
    int ck = idx & 7;
    int coord = hr >> 6, ul = hr & 63;
    int row_out = coord * 1024 + ubase + ul;
    *(uint4*)&Dst[(((long long)(bb2 * 16 + h0 + hh) * 2048) + row_out) * 128 +
                  64 + ck * 8] = *(const uint4*)&sm.e.Hs[hh][hr][ck * 8];
  }
}

// ----------------------------------------------------------- attention -----
// Per (bh, 256-q tile), 8 waves: wq=w&3 (owns 64 q via 2 Q B-frag sets),
// wt=w>>2 (t half). Triple-buffered K-loop over 32 tiles of 64 t with
// counted vmcnt(3) + raw s_barrier (drain only on peeled last iter). Every
// K/V ds_read_b128 feeds 2 MFMAs (q-sets): half the LDS-read traffic of the
// thin-wave shape. setprio(1) wraps MFMA clusters (2 waves/SIMD role-split).
// P in registers (C->A relayout via permlane32_swap). Cross-wt O partial
// sum at end via LDS (one d-half per round). Grid (bh, qt): 256 blocks =
// 1/CU; each XCD hosts 4 bh -> K/V working set ~3 MB fits its 4 MB L2.
__global__ __launch_bounds__(512, 2) void attn_kernel(
    const u16* __restrict__ Qcat, const u16* __restrict__ Kcat,
    const u16* __restrict__ vt, u16* __restrict__ AO) {
  __shared__ u16 Kl[3][64][128];   // [buf][t-row][cat 16 chunks, swizzled]
  __shared__ u16 Vl[3][64][64];    // [buf][d-row][t 8 chunks, swizzled]
  __shared__ float denl[2][256];   // [wt][q-local]
  const int bh = blockIdx.x, qt = blockIdx.y;
  const int bb = bh >> 4, h = bh & 15;
  const int q0 = qt << 8;
  const int tid = threadIdx.x;
  const int w = tid >> 6, lane = tid & 63;
  const int wq = w & 3, wt = w >> 2;
  const int l31 = lane & 31, l5 = lane >> 5;
  const u16* Qb = Qcat + (long long)bh * (2048 * 128);
  const u16* Kb = Kcat + (long long)bh * (2048 * 128);
  const u16* Vb = vt + (long long)bh * (64 * 2048);

  // Q B-frags, two q-sets: n = l31 -> q = q0+64wq+32qs+l31; k = ks*16+l5*8+j
  bf16x8 qf0[8], qf1[8];
  {
    const u16* qrow0 = Qb + (q0 + 64 * wq + l31) * 128 + l5 * 8;
    const u16* qrow1 = qrow0 + 32 * 128;
#pragma unroll
    for (int ks = 0; ks < 8; ++ks) {
      qf0[ks] = *(const bf16x8*)(qrow0 + ks * 16);
      qf1[ks] = *(const bf16x8*)(qrow1 + ks * 16);
    }
  }

  // staging address precompute (XOR-swizzled 16B chunks)
  const int ll = tid;                 // 0..511
  const int krow0 = ll >> 4;          // pass 0: rows 0..31
  const int kp = ll & 15;
  const int ksrc0 = (kp & 8) | ((kp & 7) ^ (krow0 & 7));
  const int krow1 = 32 + krow0;       // pass 1: rows 32..63
  const int ksrc1 = (kp & 8) | ((kp & 7) ^ (krow1 & 7));
  const int vd = ll >> 3;
  const int vsrc = (ll & 7) ^ (vd & 7);

  // prologue: stage tiles 0 and 1 (outstanding per wave: 6)
  gld16(((u16*)Kl[0]) + ll * 8,        Kb + krow0 * 128 + ksrc0 * 8);
  gld16(((u16*)Kl[0]) + 4096 + ll * 8, Kb + krow1 * 128 + ksrc1 * 8);
  gld16(((u16*)Vl[0]) + ll * 8,        Vb + vd * 2048 + vsrc * 8);
  gld16(((u16*)Kl[1]) + ll * 8,        Kb + (64 + krow0) * 128 + ksrc0 * 8);
  gld16(((u16*)Kl[1]) + 4096 + ll * 8, Kb + (64 + krow1) * 128 + ksrc1 * 8);
  gld16(((u16*)Vl[1]) + ll * 8,        Vb + vd * 2048 + 64 + vsrc * 8);

  f32x16 accO00, accO01, accO10, accO11;  // [qs][dq]
#pragma unroll
  for (int i = 0; i < 16; ++i) {
    accO00[i] = 0.f; accO01[i] = 0.f; accO10[i] = 0.f; accO11[i] = 0.f;
  }
  float den0 = 0.f, den1 = 0.f;

  const int krow = 32 * wt + l31;  // S-phase A row (t-local)
  const int kr7 = krow & 7;

  int cur = 0;
  for (int t = 0; t < 32; ++t) {
    // tile t ready: my 3 oldest DMAs (tile t) done, keep t+1's 3 in flight
    if (t < 31) { PIPE_BARRIER(3); } else { PIPE_BARRIER(0); }
    if (t + 2 < 32) {
      const int pf = (cur >= 1) ? cur - 1 : 2;  // (cur+2)%3
      const int t2 = (t + 2) << 6;
      u16* Kd = (u16*)Kl[pf];
      gld16(Kd + ll * 8,        Kb + (t2 + krow0) * 128 + ksrc0 * 8);
      gld16(Kd + 4096 + ll * 8, Kb + (t2 + krow1) * 128 + ksrc1 * 8);
      gld16(((u16*)Vl[pf]) + ll * 8, Vb + vd * 2048 + t2 + vsrc * 8);
    }

    // ---- S^T[t-local 32wt..][q] : 8 k-steps of 16 over cat=128, 2 q-sets
    f32x16 accS0, accS1;
#pragma unroll
    for (int i = 0; i < 16; ++i) { accS0[i] = 0.f; accS1[i] = 0.f; }
    __builtin_amdgcn_s_setprio(1);
#pragma unroll
    for (int ks = 0; ks < 8; ++ks) {
      int lc = 2 * ks + l5;
      int p = (lc & 8) | ((lc & 7) ^ kr7);
      bf16x8 ak = *(const bf16x8*)&Kl[cur][krow][p * 8];
      accS0 = mfma32(ak, qf0[ks], accS0);
      accS1 = mfma32(ak, qf1[ks], accS1);
    }
    __builtin_amdgcn_s_setprio(0);

    // ---- exp2 -> packed bf16 P (regs, v_perm pack); per-lane den partials
    BFrag A0q0, A1q0, A0q1, A1q1;
    {
      u32 D0[2], D1[2], D2[2], D3[2];
#pragma unroll
      for (int rr = 0; rr < 4; ++rr) {
        float p0 = __builtin_amdgcn_exp2f(accS0[4 * rr + 0]);
        float p1 = __builtin_amdgcn_exp2f(accS0[4 * rr + 1]);
        float p2 = __builtin_amdgcn_exp2f(accS0[4 * rr + 2]);
        float p3 = __builtin_amdgcn_exp2f(accS0[4 * rr + 3]);
        den0 += (p0 + p1) + (p2 + p3);
        u32 lo = __builtin_amdgcn_perm(__float_as_uint(p1),
                                       __float_as_uint(p0), 0x07060302u);
        u32 hi = __builtin_amdgcn_perm(__float_as_uint(p3),
                                       __float_as_uint(p2), 0x07060302u);
        if (rr == 0) { D0[0] = lo; D0[1] = hi; }
        else if (rr == 1) { D1[0] = lo; D1[1] = hi; }
        else if (rr == 2) { D2[0] = lo; D2[1] = hi; }
        else { D3[0] = lo; D3[1] = hi; }
      }
      A0q0.u[0] = D0[0]; A0q0.u[2] = D1[0]; pl32swap(A0q0.u[0], A0q0.u[2], l5);
      A0q0.u[1] = D0[1]; A0q0.u[3] = D1[1]; pl32swap(A0q0.u[1], A0q0.u[3], l5);
      A1q0.u[0] = D2[0]; A1q0.u[2] = D3[0]; pl32swap(A1q0.u[0], A1q0.u[2], l5);
      A1q0.u[1] = D2[1]; A1q0.u[3] = D3[1]; pl32swap(A1q0.u[1], A1q0.u[3], l5);
    }
    {
      u32 D0[2], D1[2], D2[2], D3[2];
#pragma unroll
      for (int rr = 0; rr < 4; ++rr) {
        float p0 = __builtin_amdgcn_exp2f(accS1[4 * rr + 0]);
        float p1 = __builtin_amdgcn_exp2f(accS1[4 * rr + 1]);
        float p2 = __builtin_amdgcn_exp2f(accS1[4 * rr + 2]);
        float p3 = __builtin_amdgcn_exp2f(accS1[4 * rr + 3]);
        den1 += (p0 + p1) + (p2 + p3);
        u32 lo = __builtin_amdgcn_perm(__float_as_uint(p1),
                                       __float_as_uint(p0), 0x07060302u);
        u32 hi = __builtin_amdgcn_perm(__float_as_uint(p3),
                                       __float_as_uint(p2), 0x07060302u);
        if (rr == 0) { D0[0] = lo; D0[1] = hi; }
        else if (rr == 1) { D1[0] = lo; D1[1] = hi; }
        else if (rr == 2) { D2[0] = lo; D2[1] = hi; }
        else { D3[0] = lo; D3[1] = hi; }
      }
      A0q1.u[0] = D0[0]; A0q1.u[2] = D1[0]; pl32swap(A0q1.u[0], A0q1.u[2], l5);
      A0q1.u[1] = D0[1]; A0q1.u[3] = D1[1]; pl32swap(A0q1.u[1], A0q1.u[3], l5);
      A1q1.u[0] = D2[0]; A1q1.u[2] = D3[0]; pl32swap(A1q1.u[0], A1q1.u[2], l5);
      A1q1.u[1] = D2[1]; A1q1.u[3] = D3[1]; pl32swap(A1q1.u[1], A1q1.u[3], l5);
    }

    // ---- O_partial[q][d] += P · V over OWN t-half (k=32); V frag reused 2x
    __builtin_amdgcn_s_setprio(1);
#pragma unroll
    for (int dq = 0; dq < 2; ++dq) {
      int d = 32 * dq + l31;
      int d7 = d & 7;
#pragma unroll
      for (int ks = 0; ks < 2; ++ks) {
        int lc = 4 * wt + 2 * ks + l5;
        bf16x8 bvf = *(const bf16x8*)&Vl[cur][d][((lc ^ d7) & 7) * 8];
        if (dq == 0) {
          accO00 = mfma32(ks ? A1q0.b : A0q0.b, bvf, accO00);
          accO10 = mfma32(ks ? A1q1.b : A0q1.b, bvf, accO10);
        } else {
          accO01 = mfma32(ks ? A1q0.b : A0q0.b, bvf, accO01);
          accO11 = mfma32(ks ? A1q1.b : A0q1.b, bvf, accO11);
        }
      }
    }
    __builtin_amdgcn_s_setprio(0);
    cur = (cur == 2) ? 0 : cur + 1;
  }

  // ---- den: lane partial covers 16 of own t-half's 32; partner has rest
  den0 += __shfl_xor(den0, 32);
  den1 += __shfl_xor(den1, 32);
  if (lane < 32) {
    denl[wt][64 * wq + lane] = den0;
    denl[wt][64 * wq + 32 + lane] = den1;
  }

  // ---- cross-wt O partial reduction via LDS scratch (Kl: f32),
  //      one d-half (dq) per round: 4 waves x 64q x 32d f32 = 32 KB
  float* Ssc = (float*)Kl;
#pragma unroll
  for (int dq = 0; dq < 2; ++dq) {
    __syncthreads();
    if (wt == 1) {
#pragma unroll
      for (int qs = 0; qs < 2; ++qs)
#pragma unroll
        for (int r = 0; r < 16; ++r) {
          int qr = (r & 3) + 8 * (r >> 2) + 4 * l5;  // 0..31
          float v = dq ? (qs ? accO11[r] : accO01[r])
                       : (qs ? accO10[r] : accO00[r]);
          Ssc[(wq * 64 + qs * 32 + qr) * 32 + l31] = v;
        }
    }
    __syncthreads();
    if (wt == 0) {
#pragma unroll
      for (int qs = 0; qs < 2; ++qs)
#pragma unroll
        for (int r = 0; r < 16; ++r) {
          int qr = (r & 3) + 8 * (r >> 2) + 4 * l5;
          int ql = 64 * wq + 32 * qs + qr;
          float inv = 1.0f / (denl[0][ql] + denl[1][ql]);
          float mine = dq ? (qs ? accO11[r] : accO01[r])
                          : (qs ? accO10[r] : accO00[r]);
          float o = (mine + Ssc[(wq * 64 + qs * 32 + qr) * 32 + l31]) * inv;
          long long base = ((long long)(bb * 2048 + q0 + ql) * 1024) + h * 64;
          AO[base + 32 * dq + l31] = f2b(o);
        }
    }
  }
}

// ----------------------------------------------------------- out GEMM -----
// 128x64 tiles, grid (16,32) = 512 blocks -> 2 blocks/CU. 4 waves in 2x2:
// wave covers 64 m x 32 n. Triple-buffered counted-vmcnt pipeline (same
// pattern as attn): vmcnt(3) + raw barrier, drain only on peeled last iter.
__global__ __launch_bounds__(256, 2) void out_gemm(
    const u16* __restrict__ AO, const u16* __restrict__ wob,
    const float* __restrict__ bo, float* __restrict__ out) {
  __shared__ u16 Al[3][128][32];
  __shared__ u16 Bl[3][64][32];
  const int n0 = blockIdx.x << 6;
  const int m0 = blockIdx.y << 7;
  const int tid = threadIdx.x;
  const int wave = tid >> 6, lane = tid & 63;
  const int g = lane >> 4, c15 = lane & 15;
  const int wm = wave & 1, wn = wave >> 1;
  const u16* Wp = wob + n0 * 1024;
  const u16* Ap = AO + m0 * 1024;
  const int srow = tid >> 2;          // 0..63
  const int scol = (tid & 3) << 3;    // 0,8,16,24

  f32x4 acc[4][2];
#pragma unroll
  for (int i = 0; i < 4; i++)
#pragma unroll
    for (int j = 0; j < 2; j++) acc[i][j] = f32x4{0.f, 0.f, 0.f, 0.f};

  // prologue: stage k-tiles 0 and 1 (outstanding per wave: 6)
  gld16(&Al[0][srow][scol],      Ap + srow * 1024 + scol);
  gld16(&Al[0][64 + srow][scol], Ap + (64 + srow) * 1024 + scol);
  gld16(&Bl[0][srow][scol],      Wp + srow * 1024 + scol);
  gld16(&Al[1][srow][scol],      Ap + srow * 1024 + 32 + scol);
  gld16(&Al[1][64 + srow][scol], Ap + (64 + srow) * 1024 + 32 + scol);
  gld16(&Bl[1][srow][scol],      Wp + srow * 1024 + 32 + scol);

  int cur = 0;
  for (int it = 0; it < 32; ++it) {
    if (it < 31) { PIPE_BARRIER(3); } else { PIPE_BARRIER(0); }
    if (it + 2 < 32) {
      const int pf = (cur >= 1) ? cur - 1 : 2;  // (cur+2)%3
      const int kn = (it + 2) << 5;
      gld16(&Al[pf][srow][scol],      Ap + srow * 1024 + kn + scol);
      gld16(&Al[pf][64 + srow][scol], Ap + (64 + srow) * 1024 + kn + scol);
      gld16(&Bl[pf][srow][scol],      Wp + srow * 1024 + kn + scol);
    }
    bf16x8 a[4], b[2];
#pragma unroll
    for (int i = 0; i < 4; i++)
      a[i] = *(const bf16x8*)&Al[cur][wm * 64 + i * 16 + c15][g * 8];
#pragma unroll
    for (int j = 0; j < 2; j++)
      b[j] = *(const bf16x8*)&Bl[cur][wn * 32 + j * 16 + c15][g * 8];
#pragma unroll
    for (int i = 0; i < 4; i++)
#pragma unroll
      for (int j = 0; j < 2; j++) acc[i][j] = mfma16(a[i], b[j], acc[i][j]);
    cur = (cur == 2) ? 0 : cur + 1;
  }
#pragma unroll
  for (int i = 0; i < 4; i++)
#pragma unroll
    for (int j = 0; j < 2; j++)
#pragma unroll
      for (int r = 0; r < 4; r++) {
        int row = m0 + wm * 64 + i * 16 + g * 4 + r;
        int col = n0 + wn * 32 + j * 16 + c15;
        out[row * 1024 + col] = acc[i][j][r] + bo[col];
      }
}

// -------------------------------------------------------------- launch -----
extern "C" void kernel_launch(void* const* d_in, const int* in_sizes, int n_in,
                              void* d_out, int out_size, void* d_ws,
                              size_t ws_size, hipStream_t stream) {
  const float* x    = (const float*)d_in[0];
  const float* Wq   = (const float*)d_in[1];
  const float* bq   = (const float*)d_in[2];
  const float* Wk   = (const float*)d_in[3];
  const float* bk   = (const float*)d_in[4];
  const float* Wv   = (const float*)d_in[5];
  const float* bv   = (const float*)d_in[6];
  const float* Wo   = (const float*)d_in[7];
  const float* bo   = (const float*)d_in[8];
  const float* Whel = (const float*)d_in[9];
  const float* bhel = (const float*)d_in[10];
  float* out = (float*)d_out;

  char* ws = (char*)d_ws;
  u16* xb   = (u16*)(ws + 0);                  //  8 MB
  u16* wb   = (u16*)(ws + 8388608);            //  6 MB (Wq|Wk|Wv)
  u16* wob  = (u16*)(ws + 14680064);           //  2 MB
  u16* whb  = (u16*)(ws + 16777216);           //  128 KB
  u16* Qcat = (u16*)(ws + 16908288);           // 16 MB  [bh][s][128]
  u16* Kcat = (u16*)(ws + 33685504);           // 16 MB
  u16* vt   = (u16*)(ws + 50462720);           //  8 MB  [bh][d][t]
  u16* AO   = (u16*)(ws + 58851328);           //  8 MB  (total ~64.1 MB)

  cast_kernel<<<dim3(8256), dim3(256), 0, stream>>>(x, Wq, Wk, Wv, Wo, Whel,
                                                    xb, wb, wob, whb);
  qkv_gemm<<<dim3(24, 32), dim3(256), 0, stream>>>(xb, wb, bq, bk, bv, whb,
                                                   bhel, Qcat, Kcat, vt);
  attn_kernel<<<dim3(32, 8), dim3(512), 0, stream>>>(Qcat, Kcat, vt, AO);
  out_gemm<<<dim3(16, 32), dim3(256), 0, stream>>>(AO, wob, bo, out);
}

// Round 4
// 217.824 us; speedup vs baseline: 1.0437x; 1.0437x over previous
//
#include <hip/hip_runtime.h>
#include <hip/hip_bf16.h>

// HelicalAttention on MI355X (gfx950).
// B=2,S=2048,E=1024,H=16,HD=64,HX=64,P=32. All heavy math in bf16 MFMA,
// fp32 accumulate. Score = (q/16)·k + (qs/8)·(ks/8) folded into one K=128
// contraction; log2(e) folded into Q so softmax uses raw exp2. Flash-style,
// no max subtraction (scores bounded).
// R12: attn reverted to R10 thin-wave pipelined form (fat-wave closed: R9/R11
// both regressed). qkv_gemm gets the R10 counted-vmcnt triple-buffer pipeline
// (profile showed it 89% stalled on the per-iter vmcnt(0) barrier drain:
// MfmaUtil 11%, busy-time == ideal MFMA time). V-transpose scratch T moved to
// its own union arm so LDS stays 51200 B -> 3 blocks/CU.

typedef unsigned short u16;
typedef unsigned int u32;
typedef __attribute__((ext_vector_type(8))) __bf16 bf16x8;
typedef __attribute__((ext_vector_type(4))) float f32x4;
typedef __attribute__((ext_vector_type(16))) float f32x16;

union BFrag { u32 u[4]; bf16x8 b; };

__device__ __forceinline__ u16 f2b(float f) {
  u32 u = __float_as_uint(f);
  u32 r = (u + 0x7fffu + ((u >> 16) & 1u)) >> 16;
  return (u16)r;
}
__device__ __forceinline__ float b2f(u16 h) {
  return __uint_as_float(((u32)h) << 16);
}

__device__ __forceinline__ f32x4 mfma16(bf16x8 a, bf16x8 b, f32x4 c) {
  return __builtin_amdgcn_mfma_f32_16x16x32_bf16(a, b, c, 0, 0, 0);
}
__device__ __forceinline__ f32x16 mfma32(bf16x8 a, bf16x8 b, f32x16 c) {
  return __builtin_amdgcn_mfma_f32_32x32x16_bf16(a, b, c, 0, 0, 0);
}

// async global->LDS, 16B per lane. LDS dest = wave-uniform base + lane*16.
__device__ __forceinline__ void gld16(void* lds, const void* g) {
  __builtin_amdgcn_global_load_lds(
      (const __attribute__((address_space(1))) unsigned int*)g,
      (__attribute__((address_space(3))) unsigned int*)lds, 16, 0, 0);
}

// a' = [a.low32, b.low32], b' = [a.high32, b.high32]  (cross-half exchange)
__device__ __forceinline__ void pl32swap(u32& a, u32& b, int l5) {
#if __has_builtin(__builtin_amdgcn_permlane32_swap)
  typedef unsigned int u32x2v __attribute__((ext_vector_type(2)));
  u32x2v r = __builtin_amdgcn_permlane32_swap(a, b, false, false);
  a = r[0];
  b = r[1];
#else
  u32 ea = __shfl_xor((int)a, 32);
  u32 eb = __shfl_xor((int)b, 32);
  u32 na = l5 ? eb : a;
  u32 nb = l5 ? b : ea;
  a = na;
  b = nb;
#endif
}

#define LOG2E 1.4426950408889634f

// counted-vmcnt barrier: each wave confirms its own oldest DMAs done, then
// raw barrier (no compiler drain). sched_barrier fences pin motion.
#define PIPE_BARRIER(N)                                         \
  do {                                                          \
    __builtin_amdgcn_sched_barrier(0);                          \
    asm volatile("s_waitcnt vmcnt(" #N ")" ::: "memory");       \
    __builtin_amdgcn_s_barrier();                               \
    __builtin_amdgcn_sched_barrier(0);                          \
  } while (0)

// ---------------------------------------------------------------- cast -----
__global__ __launch_bounds__(256) void cast_kernel(
    const float* __restrict__ x,  const float* __restrict__ wq,
    const float* __restrict__ wk, const float* __restrict__ wv,
    const float* __restrict__ wo, const float* __restrict__ whel,
    u16* __restrict__ xb, u16* __restrict__ wb, u16* __restrict__ wob,
    u16* __restrict__ whb) {
  long long q = (long long)blockIdx.x * 256 + threadIdx.x;
  const float* s; u16* d; long long base;
  if (q < 1048576)      { s = x;    d = xb;            base = 0; }
  else if (q < 1310720) { s = wq;   d = wb;            base = 1048576; }
  else if (q < 1572864) { s = wk;   d = wb + 1048576;  base = 1310720; }
  else if (q < 1835008) { s = wv;   d = wb + 2097152;  base = 1572864; }
  else if (q < 2097152) { s = wo;   d = wob;           base = 1835008; }
  else                  { s = whel; d = whb;           base = 2097152; }
  long long e = (q - base) * 4;
  float4 v = *(const float4*)(s + e);
  ushort4 o;
  o.x = f2b(v.x); o.y = f2b(v.y); o.z = f2b(v.z); o.w = f2b(v.w);
  *(ushort4*)(d + e) = o;
}

// ------------------------------------------------------- QKV GEMM + hel ----
// which=0 -> Qcat[bh][s][0:64] = q*(log2e/16); which=1 -> Kcat = k;
// which=2 -> vT[bh][d][t] = v via LDS transpose (coalesced stores).
// Triple-buffered K-loop, counted vmcnt(4) + raw s_barrier (4 DMAs/iter per
// wave; tile t+1 stays in flight across the barrier; drain only at peeled
// last iter). Fused helical epilogue (which 0/1): wave's 64x64 acc quadrant
// = one head x 64 tokens; hel = acc·Whel[h]^T + bhel -> pair-normalize ->
// scramble staged in LDS (Hs) -> coalesced uint4 stores of cols [64:128).
__global__ __launch_bounds__(256, 3) void qkv_gemm(
    const u16* __restrict__ xb, const u16* __restrict__ wb,
    const float* __restrict__ bq, const float* __restrict__ bk,
    const float* __restrict__ bv, const u16* __restrict__ whb,
    const float* __restrict__ bhel,
    u16* __restrict__ Qcat, u16* __restrict__ Kcat, u16* __restrict__ vt) {
  union SM {
    struct { u16 Al[3][128][32]; u16 Bl[3][128][32]; } m;  // 49152 B
    struct { u16 T[64][136]; } t;                          // 17408 B
    struct { u16 Th[4][32][72]; u16 Hs[2][128][64]; } e;   // 51200 B
  };
  __shared__ SM sm;
  const int nt = blockIdx.x, mt = blockIdx.y;
  const int which = nt >> 3;
  const int n0 = (nt & 7) << 7;
  const int m0 = mt << 7;
  const int tid = threadIdx.x;
  const int wave = tid >> 6, lane = tid & 63;
  const int g = lane >> 4, c15 = lane & 15;
  const int wm = wave & 1, wn = wave >> 1;
  const u16* Wp = wb + (long long)which * (1024 * 1024) + n0 * 1024;
  const u16* Ap = xb + m0 * 1024;
  const int srow = tid >> 2;          // 0..63
  const int scol = (lane & 3) << 3;   // 0,8,16,24

  f32x4 acc[4][4];
#pragma unroll
  for (int i = 0; i < 4; i++)
#pragma unroll
    for (int j = 0; j < 4; j++) acc[i][j] = f32x4{0.f, 0.f, 0.f, 0.f};

  // prologue: stage k-tiles 0 and 1 (outstanding per wave: 8)
  gld16(&sm.m.Al[0][srow][scol],      Ap + srow * 1024 + scol);
  gld16(&sm.m.Al[0][64 + srow][scol], Ap + (64 + srow) * 1024 + scol);
  gld16(&sm.m.Bl[0][srow][scol],      Wp + srow * 1024 + scol);
  gld16(&sm.m.Bl[0][64 + srow][scol], Wp + (64 + srow) * 1024 + scol);
  gld16(&sm.m.Al[1][srow][scol],      Ap + srow * 1024 + 32 + scol);
  gld16(&sm.m.Al[1][64 + srow][scol], Ap + (64 + srow) * 1024 + 32 + scol);
  gld16(&sm.m.Bl[1][srow][scol],      Wp + srow * 1024 + 32 + scol);
  gld16(&sm.m.Bl[1][64 + srow][scol], Wp + (64 + srow) * 1024 + 32 + scol);

  int cur = 0;
  for (int it = 0; it < 32; ++it) {
    // tile `it` ready: my 4 oldest DMAs done; tile it+1's 4 stay in flight
    if (it < 31) { PIPE_BARRIER(4); } else { PIPE_BARRIER(0); }
    if (it + 2 < 32) {
      const int pf = (cur >= 1) ? cur - 1 : 2;  // (cur+2)%3
      const int kn = (it + 2) << 5;
      gld16(&sm.m.Al[pf][srow][scol],      Ap + srow * 1024 + kn + scol);
      gld16(&sm.m.Al[pf][64 + srow][scol],
            Ap + (64 + srow) * 1024 + kn + scol);
      gld16(&sm.m.Bl[pf][srow][scol],      Wp + srow * 1024 + kn + scol);
      gld16(&sm.m.Bl[pf][64 + srow][scol],
            Wp + (64 + srow) * 1024 + kn + scol);
    }
    bf16x8 a[4], b[4];
#pragma unroll
    for (int i = 0; i < 4; i++)
      a[i] = *(const bf16x8*)&sm.m.Al[cur][wm * 64 + i * 16 + c15][g * 8];
#pragma unroll
    for (int j = 0; j < 4; j++)
      b[j] = *(const bf16x8*)&sm.m.Bl[cur][wn * 64 + j * 16 + c15][g * 8];
#pragma unroll
    for (int i = 0; i < 4; i++)
#pragma unroll
      for (int j = 0; j < 4; j++) acc[i][j] = mfma16(a[i], b[j], acc[i][j]);
    cur = (cur == 2) ? 0 : cur + 1;
  }

  if (which == 2) {
#pragma unroll
    for (int half = 0; half < 2; ++half) {
      __syncthreads();
      if (wn == half) {
#pragma unroll
        for (int i = 0; i < 4; i++)
#pragma unroll
          for (int j = 0; j < 4; j++)
#pragma unroll
            for (int r = 0; r < 4; r++) {
              int nloc = j * 16 + c15;                  // 0..63
              int mloc = wm * 64 + i * 16 + g * 4 + r;  // 0..127
              float v = acc[i][j][r] + bv[n0 + half * 64 + nloc];
              sm.t.T[nloc][mloc] = f2b(v);
            }
      }
      __syncthreads();
#pragma unroll
      for (int it = 0; it < 4; ++it) {
        int idx = it * 256 + tid;
        int row = idx >> 4;         // 0..63
        int cm = (idx & 15) * 8;    // 0..120
        int col = n0 + half * 64 + row;
        int hh = col >> 6, dd = col & 63;
        int m = m0 + cm;
        int bb2 = m >> 11, s = m & 2047;
        *(uint4*)&vt[(((bb2 * 16 + hh) * 64) + dd) * 2048 + s] =
            *(const uint4*)&sm.t.T[row][cm];
      }
    }
    return;
  }

  // ---------------- fused helical epilogue (which 0 or 1) ----------------
  const float* bias = (which == 0) ? bq : bk;
  const float fold = (which == 0) ? (0.0625f * LOG2E) : 1.0f;
  const float osc  = (which == 0) ? (0.125f * LOG2E) : 0.125f;
  const int h0 = n0 >> 6;
  const int hsel = h0 + wn;  // wave's head (block spans 2 heads)
  u16* Dst = ((which == 0) ? Qcat : Kcat);

  // Whel B-frags direct from global (once per block)
  bf16x8 wf[2][4];  // [kh][nf]
#pragma unroll
  for (int kh = 0; kh < 2; ++kh)
#pragma unroll
    for (int nf = 0; nf < 4; ++nf)
      wf[kh][nf] = *(const bf16x8*)(whb + hsel * 4096 + (nf * 16 + c15) * 64 +
                                    kh * 32 + g * 8);

  __syncthreads();  // all main-loop LDS reads done; safe to repurpose
  const int bb2 = m0 >> 11;
  const int ubase = (m0 & 2047) >> 1;

#pragma unroll
  for (int half = 0; half < 2; ++half) {
    // main output write (cols [0:64)) + per-wave Th tile (raw bf16, no fold)
#pragma unroll
    for (int i2 = 0; i2 < 2; ++i2) {
      int i = half * 2 + i2;
#pragma unroll
      for (int j = 0; j < 4; ++j)
#pragma unroll
        for (int r = 0; r < 4; ++r) {
          int row = m0 + wm * 64 + i * 16 + g * 4 + r;  // token 0..4095
          int col = n0 + wn * 64 + j * 16 + c15;
          float vraw = acc[i][j][r] + bias[col];
          int bb = row >> 11, s = row & 2047;
          int d = col & 63;
          Dst[(((long long)(bb * 16 + hsel) * 2048) + s) * 128 + d] =
              f2b(vraw * fold);
          sm.e.Th[wave][i2 * 16 + g * 4 + r][j * 16 + c15] = f2b(vraw);
        }
    }
    // hel = Th(32 tok x 64 d) · Whel[h]^T   [Th wave-private, in-order LDS]
    f32x4 hacc[2][4];
#pragma unroll
    for (int mf = 0; mf < 2; ++mf)
#pragma unroll
      for (int nf = 0; nf < 4; ++nf) hacc[mf][nf] = f32x4{0.f, 0.f, 0.f, 0.f};
#pragma unroll
    for (int kh = 0; kh < 2; ++kh) {
      bf16x8 a0 = *(const bf16x8*)&sm.e.Th[wave][c15][kh * 32 + g * 8];
      bf16x8 a1 = *(const bf16x8*)&sm.e.Th[wave][16 + c15][kh * 32 + g * 8];
#pragma unroll
      for (int nf = 0; nf < 4; ++nf) {
        hacc[0][nf] = mfma16(a0, wf[kh][nf], hacc[0][nf]);
        hacc[1][nf] = mfma16(a1, wf[kh][nf], hacc[1][nf]);
      }
    }
    // + bhel, pair-normalize (partner e^1 = lane^1), scramble-stage into Hs
#pragma unroll
    for (int mf = 0; mf < 2; ++mf)
#pragma unroll
      for (int nf = 0; nf < 4; ++nf)
#pragma unroll
        for (int r = 0; r < 4; ++r) {
          int e = nf * 16 + c15;
          float v = hacc[mf][nf][r] + bhel[hsel * 64 + e];
          float pp = __shfl_xor(v, 1);
          float nn = sqrtf(v * v + pp * pp);
          float o = v / fmaxf(nn, 1e-12f) * osc;
          int tl = wm * 64 + half * 32 + mf * 16 + g * 4 + r;  // token-local
          sm.e.Hs[wn][(e & 1) * 64 + (tl >> 1)][(e & ~1) | (tl & 1)] = f2b(o);
        }
  }
  __syncthreads();
  // coalesced stores of hel region: 2 heads x 128 Hs-rows x 8 uint4 chunks
#pragma unroll
  for (int it = 0; it < 8; ++it) {
    int idx = it * 256 + tid;  // 0..2047
    int hh = idx >> 10;
    int hr = (idx >> 3) & 127;
    int ck = idx & 7;
    int coord = hr >> 6, ul = hr & 63;
    int row_out = coord * 1024 + ubase + ul;
    *(uint4*)&Dst[(((long long)(bb2 * 16 + h0 + hh) * 2048) + row_out) * 128 +
                  64 + ck * 8] = *(const uint4*)&sm.e.Hs[hh][hr][ck * 8];
  }
}

// ----------------------------------------------------------- attention -----
// Per (bh, 128-q tile), 8 waves: wq=w&3, wt=w>>2 (t half). Triple-buffered
// K-loop over 32 tiles of 64 t with counted vmcnt(3) + raw s_barrier (no
// drain in main loop; peeled last iter drains). P in registers (C->A
// relayout via permlane32_swap). Cross-wt O partial sum at end via LDS.
// Grid (bh, qt): each XCD hosts 4 bh -> K/V working set ~3 MB fits its L2.
__global__ __launch_bounds__(512, 4) void attn_kernel(
    const u16* __restrict__ Qcat, const u16* __restrict__ Kcat,
    const u16* __restrict__ vt, u16* __restrict__ AO) {
  __shared__ u16 Kl[3][64][128];   // [buf][t-row][cat 16 chunks, swizzled]
  __shared__ u16 Vl[3][64][64];    // [buf][d-row][t 8 chunks, swizzled]
  __shared__ float denl[2][128];   // [wt][q-local]
  const int bh = blockIdx.x, qt = blockIdx.y;
  const int bb = bh >> 4, h = bh & 15;
  const int q0 = qt << 7;
  const int tid = threadIdx.x;
  const int w = tid >> 6, lane = tid & 63;
  const int wq = w & 3, wt = w >> 2;
  const int l31 = lane & 31, l5 = lane >> 5;
  const u16* Qb = Qcat + (long long)bh * (2048 * 128);
  const u16* Kb = Kcat + (long long)bh * (2048 * 128);
  const u16* Vb = vt + (long long)bh * (64 * 2048);

  // Q B-frags: n = l31 -> q = q0+32wq+l31; k = ks*16+l5*8+j
  bf16x8 qf[8];
  {
    const u16* qrow = Qb + (q0 + 32 * wq + l31) * 128 + l5 * 8;
#pragma unroll
    for (int ks = 0; ks < 8; ++ks) qf[ks] = *(const bf16x8*)(qrow + ks * 16);
  }

  // staging address precompute (XOR-swizzled 16B chunks)
  const int ll = tid;                 // 0..511
  const int krow0 = ll >> 4;          // pass 0: rows 0..31
  const int kp = ll & 15;
  const int ksrc0 = (kp & 8) | ((kp & 7) ^ (krow0 & 7));
  const int krow1 = 32 + krow0;       // pass 1: rows 32..63
  const int ksrc1 = (kp & 8) | ((kp & 7) ^ (krow1 & 7));
  const int vd = ll >> 3;
  const int vsrc = (ll & 7) ^ (vd & 7);

  // prologue: stage tiles 0 and 1 (outstanding per wave: 6)
  gld16(((u16*)Kl[0]) + ll * 8,        Kb + krow0 * 128 + ksrc0 * 8);
  gld16(((u16*)Kl[0]) + 4096 + ll * 8, Kb + krow1 * 128 + ksrc1 * 8);
  gld16(((u16*)Vl[0]) + ll * 8,        Vb + vd * 2048 + vsrc * 8);
  gld16(((u16*)Kl[1]) + ll * 8,        Kb + (64 + krow0) * 128 + ksrc0 * 8);
  gld16(((u16*)Kl[1]) + 4096 + ll * 8, Kb + (64 + krow1) * 128 + ksrc1 * 8);
  gld16(((u16*)Vl[1]) + ll * 8,        Vb + vd * 2048 + 64 + vsrc * 8);

  f32x16 accO0, accO1;
#pragma unroll
  for (int i = 0; i < 16; ++i) { accO0[i] = 0.f; accO1[i] = 0.f; }
  float den = 0.f;

  const int krow = 32 * wt + l31;  // S-phase A row (t-local)
  const int kr7 = krow & 7;

  int cur = 0;
  for (int t = 0; t < 32; ++t) {
    // tile t ready: my 3 oldest DMAs (tile t) done, keep t+1's 3 in flight
    if (t < 31) { PIPE_BARRIER(3); } else { PIPE_BARRIER(0); }
    if (t + 2 < 32) {
      const int pf = (cur >= 1) ? cur - 1 : 2;  // (cur+2)%3
      const int t2 = (t + 2) << 6;
      u16* Kd = (u16*)Kl[pf];
      gld16(Kd + ll * 8,        Kb + (t2 + krow0) * 128 + ksrc0 * 8);
      gld16(Kd + 4096 + ll * 8, Kb + (t2 + krow1) * 128 + ksrc1 * 8);
      gld16(((u16*)Vl[pf]) + ll * 8, Vb + vd * 2048 + t2 + vsrc * 8);
    }

    // ---- S^T[t-local 32wt..][q 32wq..] : 8 k-steps of 16 over cat=128
    f32x16 accS;
#pragma unroll
    for (int i = 0; i < 16; ++i) accS[i] = 0.f;
#pragma unroll
    for (int ks = 0; ks < 8; ++ks) {
      int lc = 2 * ks + l5;
      int p = (lc & 8) | ((lc & 7) ^ kr7);
      bf16x8 ak = *(const bf16x8*)&Kl[cur][krow][p * 8];
      accS = mfma32(ak, qf[ks], accS);
    }

    // ---- exp2 -> packed bf16 P (regs, v_perm pack); per-lane den partial
    u32 D0[2], D1[2], D2[2], D3[2];
#pragma unroll
    for (int rr = 0; rr < 4; ++rr) {
      float p0 = __builtin_amdgcn_exp2f(accS[4 * rr + 0]);
      float p1 = __builtin_amdgcn_exp2f(accS[4 * rr + 1]);
      float p2 = __builtin_amdgcn_exp2f(accS[4 * rr + 2]);
      float p3 = __builtin_amdgcn_exp2f(accS[4 * rr + 3]);
      den += (p0 + p1) + (p2 + p3);
      u32 lo = __builtin_amdgcn_perm(__float_as_uint(p1), __float_as_uint(p0),
                                     0x07060302u);
      u32 hi = __builtin_amdgcn_perm(__float_as_uint(p3), __float_as_uint(p2),
                                     0x07060302u);
      if (rr == 0) { D0[0] = lo; D0[1] = hi; }
      else if (rr == 1) { D1[0] = lo; D1[1] = hi; }
      else if (rr == 2) { D2[0] = lo; D2[1] = hi; }
      else { D3[0] = lo; D3[1] = hi; }
    }
    // cross-half exchange: build A-frags (m=q, k=t-local within own half)
    BFrag A0, A1;
    A0.u[0] = D0[0]; A0.u[2] = D1[0]; pl32swap(A0.u[0], A0.u[2], l5);
    A0.u[1] = D0[1]; A0.u[3] = D1[1]; pl32swap(A0.u[1], A0.u[3], l5);
    A1.u[0] = D2[0]; A1.u[2] = D3[0]; pl32swap(A1.u[0], A1.u[2], l5);
    A1.u[1] = D2[1]; A1.u[3] = D3[1]; pl32swap(A1.u[1], A1.u[3], l5);

    // ---- O_partial[q 32wq..][d 0..63] += P · V over OWN t-half (k=32)
#pragma unroll
    for (int dq = 0; dq < 2; ++dq) {
      int d = 32 * dq + l31;
      int d7 = d & 7;
#pragma unroll
      for (int ks = 0; ks < 2; ++ks) {
        int lc = 4 * wt + 2 * ks + l5;
        bf16x8 bvf = *(const bf16x8*)&Vl[cur][d][((lc ^ d7) & 7) * 8];
        if (dq == 0) accO0 = mfma32(ks ? A1.b : A0.b, bvf, accO0);
        else         accO1 = mfma32(ks ? A1.b : A0.b, bvf, accO1);
      }
    }
    cur = (cur == 2) ? 0 : cur + 1;
  }

  // ---- den: lane partial covers 16 of own t-half's 32; partner has rest
  den += __shfl_xor(den, 32);
  if (lane < 32) denl[wt][32 * wq + lane] = den;
  __syncthreads();

  // ---- cross-wt O partial reduction via LDS scratch (reuse Kl: f32)
  float* S = (float*)Kl;
  if (wt == 1) {
#pragma unroll
    for (int r = 0; r < 16; ++r) {
      int qr = (r & 3) + 8 * (r >> 2) + 4 * l5;  // 0..31
      S[(wq * 32 + qr) * 64 + l31] = accO0[r];
      S[(wq * 32 + qr) * 64 + 32 + l31] = accO1[r];
    }
  }
  __syncthreads();
  if (wt == 0) {
#pragma unroll
    for (int r = 0; r < 16; ++r) {
      int qr = (r & 3) + 8 * (r >> 2) + 4 * l5;
      int ql = 32 * wq + qr;
      float inv = 1.0f / (denl[0][ql] + denl[1][ql]);
      float o0 = (accO0[r] + S[(wq * 32 + qr) * 64 + l31]) * inv;
      float o1 = (accO1[r] + S[(wq * 32 + qr) * 64 + 32 + l31]) * inv;
      long long base = ((long long)(bb * 2048 + q0 + ql) * 1024) + h * 64;
      AO[base + l31] = f2b(o0);
      AO[base + 32 + l31] = f2b(o1);
    }
  }
}

// ----------------------------------------------------------- out GEMM -----
// 128x64 tiles, grid (16,32) = 512 blocks -> 2 blocks/CU. 4 waves in 2x2:
// wave covers 64 m x 32 n. Triple-buffered counted-vmcnt pipeline (same
// pattern as attn): vmcnt(3) + raw barrier, drain only on peeled last iter.
__global__ __launch_bounds__(256, 2) void out_gemm(
    const u16* __restrict__ AO, const u16* __restrict__ wob,
    const float* __restrict__ bo, float* __restrict__ out) {
  __shared__ u16 Al[3][128][32];
  __shared__ u16 Bl[3][64][32];
  const int n0 = blockIdx.x << 6;
  const int m0 = blockIdx.y << 7;
  const int tid = threadIdx.x;
  const int wave = tid >> 6, lane = tid & 63;
  const int g = lane >> 4, c15 = lane & 15;
  const int wm = wave & 1, wn = wave >> 1;
  const u16* Wp = wob + n0 * 1024;
  const u16* Ap = AO + m0 * 1024;
  const int srow = tid >> 2;          // 0..63
  const int scol = (tid & 3) << 3;    // 0,8,16,24

  f32x4 acc[4][2];
#pragma unroll
  for (int i = 0; i < 4; i++)
#pragma unroll
    for (int j = 0; j < 2; j++) acc[i][j] = f32x4{0.f, 0.f, 0.f, 0.f};

  // prologue: stage k-tiles 0 and 1 (outstanding per wave: 6)
  gld16(&Al[0][srow][scol],      Ap + srow * 1024 + scol);
  gld16(&Al[0][64 + srow][scol], Ap + (64 + srow) * 1024 + scol);
  gld16(&Bl[0][srow][scol],      Wp + srow * 1024 + scol);
  gld16(&Al[1][srow][scol],      Ap + srow * 1024 + 32 + scol);
  gld16(&Al[1][64 + srow][scol], Ap + (64 + srow) * 1024 + 32 + scol);
  gld16(&Bl[1][srow][scol],      Wp + srow * 1024 + 32 + scol);

  int cur = 0;
  for (int it = 0; it < 32; ++it) {
    if (it < 31) { PIPE_BARRIER(3); } else { PIPE_BARRIER(0); }
    if (it + 2 < 32) {
      const int pf = (cur >= 1) ? cur - 1 : 2;  // (cur+2)%3
      const int kn = (it + 2) << 5;
      gld16(&Al[pf][srow][scol],      Ap + srow * 1024 + kn + scol);
      gld16(&Al[pf][64 + srow][scol], Ap + (64 + srow) * 1024 + kn + scol);
      gld16(&Bl[pf][srow][scol],      Wp + srow * 1024 + kn + scol);
    }
    bf16x8 a[4], b[2];
#pragma unroll
    for (int i = 0; i < 4; i++)
      a[i] = *(const bf16x8*)&Al[cur][wm * 64 + i * 16 + c15][g * 8];
#pragma unroll
    for (int j = 0; j < 2; j++)
      b[j] = *(const bf16x8*)&Bl[cur][wn * 32 + j * 16 + c15][g * 8];
#pragma unroll
    for (int i = 0; i < 4; i++)
#pragma unroll
      for (int j = 0; j < 2; j++) acc[i][j] = mfma16(a[i], b[j], acc[i][j]);
    cur = (cur == 2) ? 0 : cur + 1;
  }
#pragma unroll
  for (int i = 0; i < 4; i++)
#pragma unroll
    for (int j = 0; j < 2; j++)
#pragma unroll
      for (int r = 0; r < 4; r++) {
        int row = m0 + wm * 64 + i * 16 + g * 4 + r;
        int col = n0 + wn * 32 + j * 16 + c15;
        out[row * 1024 + col] = acc[i][j][r] + bo[col];
      }
}

// -------------------------------------------------------------- launch -----
extern "C" void kernel_launch(void* const* d_in, const int* in_sizes, int n_in,
                              void* d_out, int out_size, void* d_ws,
                              size_t ws_size, hipStream_t stream) {
  const float* x    = (const float*)d_in[0];
  const float* Wq   = (const float*)d_in[1];
  const float* bq   = (const float*)d_in[2];
  const float* Wk   = (const float*)d_in[3];
  const float* bk   = (const float*)d_in[4];
  const float* Wv   = (const float*)d_in[5];
  const float* bv   = (const float*)d_in[6];
  const float* Wo   = (const float*)d_in[7];
  const float* bo   = (const float*)d_in[8];
  const float* Whel = (const float*)d_in[9];
  const float* bhel = (const float*)d_in[10];
  float* out = (float*)d_out;

  char* ws = (char*)d_ws;
  u16* xb   = (u16*)(ws + 0);                  //  8 MB
  u16* wb   = (u16*)(ws + 8388608);            //  6 MB (Wq|Wk|Wv)
  u16* wob  = (u16*)(ws + 14680064);           //  2 MB
  u16* whb  = (u16*)(ws + 16777216);           //  128 KB
  u16* Qcat = (u16*)(ws + 16908288);           // 16 MB  [bh][s][128]
  u16* Kcat = (u16*)(ws + 33685504);           // 16 MB
  u16* vt   = (u16*)(ws + 50462720);           //  8 MB  [bh][d][t]
  u16* AO   = (u16*)(ws + 58851328);           //  8 MB  (total ~64.1 MB)

  cast_kernel<<<dim3(8256), dim3(256), 0, stream>>>(x, Wq, Wk, Wv, Wo, Whel,
                                                    xb, wb, wob, whb);
  qkv_gemm<<<dim3(24, 32), dim3(256), 0, stream>>>(xb, wb, bq, bk, bv, whb,
                                                   bhel, Qcat, Kcat, vt);
  attn_kernel<<<dim3(32, 16), dim3(512), 0, stream>>>(Qcat, Kcat, vt, AO);
  out_gemm<<<dim3(16, 32), dim3(256), 0, stream>>>(AO, wob, bo, out);
}